// Round 12
// baseline (69.981 us; speedup 1.0000x reference)
//
#include <hip/hip_runtime.h>
#include <hip/hip_bf16.h>

// 3x3 s1 p1 conv: B=16, CIN=128, H=W=56, COUT=256, K = 9*128.
// Pipeline: (1) wreorder5: W fp32 -> bf16 chunk-linear wb5[kt][kgrp][o] (+zero pg)
//           (2) nhwc:      X fp32 NCHW -> bf16 NHWC xin[n][c]  (n global linear)
//           (3) conv12:    implicit GEMM, 784 blocks x 256 thr (4 waves 2Mx2N),
//               tile 128co x 128sp, BK=32, A+B LDS dbuf 32KB -> 4 blocks/CU
//               (cross-block phase overlap), ONE barrier + ONE aged vmcnt(0)
//               per K-step, stage-after-barrier, compiler-scheduled interior.
//               (conv11 bug fixed: 2nd-chunk LDS dest is +2048 u16, not +4096.)
#define CIN_   128
#define HW_    56
#define LHW_   3136
#define COUT_  256
#define KTOT_  1152

typedef unsigned short u16;
typedef __attribute__((ext_vector_type(8))) short short8v;   // 8 bf16
typedef __attribute__((ext_vector_type(4))) float f32x4;

__device__ __forceinline__ u16 f2bf(float f) {
  union { float f; unsigned u; } v; v.f = f;
  unsigned u = v.u;
  u += 0x7fffu + ((u >> 16) & 1u);   // RNE
  return (u16)(u >> 16);
}
__device__ __forceinline__ unsigned pack2(u16 a, u16 b) {
  return (unsigned)a | ((unsigned)b << 16);
}

// ---- (1) chunk-linear weight reorder + zero page.
// 16B chunk s = kt*1024 + kgrp*256 + o  (kt 0..35, kgrp 0..3, o 0..255) holds
// w[o][ch*9+t] for t = kt>>2, ch = (kt&3)*32 + kgrp*8 + 0..7 (k ascending).
__global__ void wreorder5_kernel(const float* __restrict__ w, u16* __restrict__ wb5,
                                 u16* __restrict__ zp) {
  if (blockIdx.x == 0 && threadIdx.x < 16) {
    uint4 z; z.x = z.y = z.z = z.w = 0u;
    reinterpret_cast<uint4*>(zp)[threadIdx.x] = z;   // 256B zero page
  }
  int j = blockIdx.x * 256 + threadIdx.x;   // 73728 = 2 * 36864
  int half = j & 1;
  int s    = j >> 1;            // chunk 0..36863
  int o    = s & 255;
  int kgrp = (s >> 8) & 3;
  int kt   = s >> 10;
  int t    = kt >> 2;
  int ch   = (kt & 3) * 32 + kgrp * 8 + half * 4;
  const float* src = w + (size_t)o * KTOT_ + (size_t)ch * 9 + t;
  ushort4 r;
  r.x = f2bf(src[0]);  r.y = f2bf(src[9]);
  r.z = f2bf(src[18]); r.w = f2bf(src[27]);
  *reinterpret_cast<ushort4*>(wb5 + (size_t)s * 8 + half * 4) = r;
}

// ---- legacy weight reorder for fallback A: wb[(t*256+o)*128 + c]
__global__ void wreorder_kernel(const float* __restrict__ w, u16* __restrict__ wb) {
  int j = blockIdx.x * 256 + threadIdx.x;
  int c4 = j & 31;
  int o  = (j >> 5) & 255;
  int t  = j >> 13;
  const float* src = w + (size_t)o * KTOT_ + t;
  ushort4 r;
  r.x = f2bf(src[(c4 * 4 + 0) * 9]);
  r.y = f2bf(src[(c4 * 4 + 1) * 9]);
  r.z = f2bf(src[(c4 * 4 + 2) * 9]);
  r.w = f2bf(src[(c4 * 4 + 3) * 9]);
  *reinterpret_cast<ushort4*>(wb + ((size_t)(t * 256 + o) * 128 + c4 * 4)) = r;
}

// ---- (2) NCHW fp32 -> NHWC bf16 transpose (LDS-tiled, 64 pos x 128 ch)
#define TLDSW_ 136
__global__ __launch_bounds__(256) void nhwc_kernel(
    const float* __restrict__ in, u16* __restrict__ xin) {
  __shared__ u16 ts[64 * TLDSW_];
  const int bp = blockIdx.x;          // 784 = 16 * 49
  const int b = bp / 49;
  const int pos0 = (bp % 49) * 64;
  const int tid = threadIdx.x;
  const float* ib = in + (size_t)b * CIN_ * LHW_ + pos0;
  {
    const int p  = tid & 63;
    const int c0 = (tid >> 6) * 32;
    #pragma unroll
    for (int i = 0; i < 32; ++i)
      ts[p * TLDSW_ + c0 + i] = f2bf(ib[(size_t)(c0 + i) * LHW_ + p]);
  }
  __syncthreads();
  {
    const int p  = tid >> 2;
    const int c0 = (tid & 3) * 32;
    u16* dst = xin + ((size_t)b * LHW_ + pos0 + p) * CIN_ + c0;
    const u16* srcr = &ts[p * TLDSW_ + c0];
    #pragma unroll
    for (int j = 0; j < 4; ++j)
      reinterpret_cast<uint4*>(dst)[j] =
          *reinterpret_cast<const uint4*>(srcr + j * 8);
  }
}

// ---- (3) main conv
__device__ __forceinline__ void gload_lds16(const void* g, void* l) {
  __builtin_amdgcn_global_load_lds(
      (const __attribute__((address_space(1))) void*)g,
      (__attribute__((address_space(3))) void*)l, 16, 0, 0);
}

__global__ __launch_bounds__(256, 4) void conv12_kernel(
    const u16* __restrict__ xin, const u16* __restrict__ wb5,
    const float* __restrict__ bias, const u16* __restrict__ zpage,
    float* __restrict__ out)
{
  // A: chunk (kgrp 0..3, o 0..127) at u16 off (kgrp*128+o)*8    (8 KB/buf)
  // B: chunk (kgrp 0..3, p 0..127) at u16 off (kgrp*128+p)*8    (8 KB/buf)
  __shared__ __align__(16) u16 alds[2][4096];
  __shared__ __align__(16) u16 blds[2][4096];   // 32 KB total -> 4 blocks/CU

  const int tid  = threadIdx.x;
  const int lane = tid & 63;
  const int wid  = tid >> 6;
  const int wm   = wid & 1;     // 64-cout half of 128
  const int wn   = wid >> 1;    // 64-sp half of 128
  const int lr   = lane & 15;
  const int lg   = lane >> 4;

  // XCD-chunked bijective swizzle (784 = 8*98); co-halves paired on same nt.
  const int g   = (blockIdx.x & 7) * 98 + (blockIdx.x >> 3);
  const int coh = g & 1;        // cout half of 256
  const int nt  = g >> 1;       // 0..391 spatial tile of 128 positions

  // ---- B staging geometry: thread owns position p, kgroups kga and kga+2
  const int p   = tid & 127;
  const int kga = tid >> 7;     // 0/1
  const int n   = nt * 128 + p; // global linear position (xin is [n][c])
  const int ll  = n % LHW_;
  const int py  = ll / HW_;
  const int px  = ll - py * HW_;
  const u16* xp = xin + (size_t)n * CIN_ + kga * 8;
  unsigned okm = 0;
  #pragma unroll
  for (int t = 0; t < 9; ++t) {
    int yy = py + t / 3 - 1, xx = px + t % 3 - 1;
    if ((unsigned)yy < (unsigned)HW_ && (unsigned)xx < (unsigned)HW_)
      okm |= 1u << t;
  }

  const int ldso = (tid & ~63) * 8;      // u16 offset of this thread's chunk base
  // thread's chunks: tid (kgrp=kga, pos/o) and tid+256 (kgrp=kga+2) -> +2048 u16

  auto stage = [&](int kt, int h) {
    // A: linear stream; chunks tid and tid+256
    const u16* sa = wb5 + ((size_t)kt * 1024 + kga * 256 + coh * 128 + p) * 8;
    gload_lds16(sa,        alds[h] + ldso);
    gload_lds16(sa + 4096, alds[h] + ldso + 2048);   // kgrp += 2
    // B: NHWC gather at tap offset; channels (kt&3)*32 + kgrp*8
    const int t    = kt >> 2;
    const int dy   = t / 3, dx = t - dy * 3;
    const int doff = ((dy - 1) * HW_ + (dx - 1)) * CIN_ + ((kt & 3) << 5);
    const bool ok  = (okm >> t) & 1;
    const u16* sb  = ok ? xp + doff : zpage;
    const u16* sb1 = ok ? sb + 16 : zpage;           // kgrp += 2
    gload_lds16(sb,  blds[h] + ldso);
    gload_lds16(sb1, blds[h] + ldso + 2048);
  };

  // frag LDS bases (u16)
  const int abase = (lg * 128 + wm * 64 + lr) * 8;
  const int bbase = (lg * 128 + wn * 64 + lr) * 8;

  f32x4 acc[4][4];
  #pragma unroll
  for (int i = 0; i < 4; ++i)
    #pragma unroll
    for (int j = 0; j < 4; ++j)
      acc[i][j] = f32x4{0.f, 0.f, 0.f, 0.f};

  stage(0, 0);   // prologue: K-step 0 in flight

  #pragma unroll 1
  for (int kt = 0; kt < 36; ++kt) {
    const int h = kt & 1;
    // drain loads issued one full K-step ago (~free), publish buffer h;
    // the same barrier proves all waves finished reading h^1 -> WAR-safe stage.
    asm volatile("s_waitcnt vmcnt(0)" ::: "memory");
    __builtin_amdgcn_s_barrier();
    asm volatile("" ::: "memory");
    if (kt < 35) stage(kt + 1, h ^ 1);

    short8v a[4], bv[4];
    #pragma unroll
    for (int ai = 0; ai < 4; ++ai)
      a[ai] = *reinterpret_cast<const short8v*>(&alds[h][abase + ai * 128]);
    #pragma unroll
    for (int nj = 0; nj < 4; ++nj)
      bv[nj] = *reinterpret_cast<const short8v*>(&blds[h][bbase + nj * 128]);
    #pragma unroll
    for (int ai = 0; ai < 4; ++ai)
      #pragma unroll
      for (int nj = 0; nj < 4; ++nj)
        acc[ai][nj] = __builtin_amdgcn_mfma_f32_16x16x32_bf16(
            a[ai], bv[nj], acc[ai][nj], 0, 0, 0);
    asm volatile("" ::: "memory");   // keep reads inside their K-step
  }

  // epilogue: D col = lr (spatial), row = lg*4+rr (cout)
  #pragma unroll
  for (int nj = 0; nj < 4; ++nj) {
    const int nb0 = nt * 128 + wn * 64 + nj * 16;   // 16-aligned: one image
    const int ob  = nb0 / LHW_;
    const int ol  = nb0 - ob * LHW_;
    float* obp = out + (size_t)ob * COUT_ * LHW_ + ol + lr;
    #pragma unroll
    for (int ai = 0; ai < 4; ++ai) {
      const int o = coh * 128 + wm * 64 + ai * 16 + lg * 4;
      const float4 bs = *reinterpret_cast<const float4*>(&bias[o]);
      obp[(size_t)(o + 0) * LHW_] = acc[ai][nj][0] + bs.x;
      obp[(size_t)(o + 1) * LHW_] = acc[ai][nj][1] + bs.y;
      obp[(size_t)(o + 2) * LHW_] = acc[ai][nj][2] + bs.z;
      obp[(size_t)(o + 3) * LHW_] = acc[ai][nj][3] + bs.w;
    }
  }
}

// ---------------- fallback A (ws fits wb only): round-2 kernel ----
#define NF_    7
#define SCOLS_ 58
#define SPP_   232
#define CSTR_  128
__global__ __launch_bounds__(256, 2) void conv2_kernel(
    const float* __restrict__ in, const u16* __restrict__ wb,
    const float* __restrict__ bias, float* __restrict__ out)
{
  __shared__ u16 xs[SPP_ * CSTR_];
  const int tid  = threadIdx.x;
  const int lane = tid & 63;
  const int wid  = tid >> 6;
  const int lr   = lane & 15;
  const int lg   = lane >> 4;
  const int bid = blockIdx.x;
  const int ch  = bid & 1;
  const int ty  = (bid >> 1) % 28;
  const int b   = bid / 56;
  const float* inb = in + (size_t)b * CIN_ * LHW_;
  const int iy0 = ty * 2 - 1;

  #pragma unroll 1
  for (int i = 0; i < 15; ++i) {
    int idx = i * 256 + tid;
    if (idx < SPP_ * 16) {
      int cg  = idx / SPP_;
      int spp = idx - cg * SPP_;
      int rr  = spp / SCOLS_;
      int cc  = spp - rr * SCOLS_;
      int iy  = iy0 + rr;
      int ix  = cc - 1;
      bool ok = ((unsigned)iy < (unsigned)HW_) && ((unsigned)ix < (unsigned)HW_);
      const float* pp = inb + (size_t)cg * 8 * LHW_ + iy * HW_ + ix;
      u16 v[8];
      #pragma unroll
      for (int jj = 0; jj < 8; ++jj)
        v[jj] = f2bf(ok ? pp[jj * LHW_] : 0.f);
      uint4 pk;
      pk.x = pack2(v[0], v[1]); pk.y = pack2(v[2], v[3]);
      pk.z = pack2(v[4], v[5]); pk.w = pack2(v[6], v[7]);
      *reinterpret_cast<uint4*>(&xs[spp * CSTR_ + ((cg * 8) ^ ((spp & 7) << 3))]) = pk;
    }
  }
  int spp0[NF_];
  #pragma unroll
  for (int nf = 0; nf < NF_; ++nf) {
    int sp = nf * 16 + lr;
    int r  = (sp >= 56) ? 1 : 0;
    int x  = sp - r * 56;
    spp0[nf] = (r + 1) * SCOLS_ + x + 1;
  }
  f32x4 acc[2][NF_];
  #pragma unroll
  for (int m = 0; m < 2; ++m)
    #pragma unroll
    for (int nf = 0; nf < NF_; ++nf)
      acc[m][nf] = f32x4{0.f, 0.f, 0.f, 0.f};
  __syncthreads();
  const u16* wt0 = wb + (size_t)(ch * 128 + wid * 32 + lr) * CSTR_ + lg * 8;
  #pragma unroll 1
  for (int t = 0; t < 9; ++t) {
    const int dspp = (t / 3 - 1) * SCOLS_ + (t % 3 - 1);
    const u16* wt = wt0 + (size_t)t * 256 * CSTR_;
    #pragma unroll
    for (int c0i = 0; c0i < 4; ++c0i) {
      const int c0 = c0i * 32;
      short8v a0 = *reinterpret_cast<const short8v*>(wt + c0);
      short8v a1 = *reinterpret_cast<const short8v*>(wt + 16 * CSTR_ + c0);
      short8v bv[NF_];
      #pragma unroll
      for (int nf = 0; nf < NF_; ++nf) {
        int spp = spp0[nf] + dspp;
        int off = spp * CSTR_ + ((c0 + lg * 8) ^ ((spp & 7) << 3));
        bv[nf] = *reinterpret_cast<const short8v*>(&xs[off]);
      }
      #pragma unroll
      for (int nf = 0; nf < NF_; ++nf) {
        acc[0][nf] = __builtin_amdgcn_mfma_f32_16x16x32_bf16(a0, bv[nf], acc[0][nf], 0, 0, 0);
        acc[1][nf] = __builtin_amdgcn_mfma_f32_16x16x32_bf16(a1, bv[nf], acc[1][nf], 0, 0, 0);
      }
    }
  }
  float* ob = out + (size_t)b * COUT_ * LHW_ + ty * 112;
  const int obase = ch * 128 + wid * 32 + lg * 4;
  #pragma unroll
  for (int m = 0; m < 2; ++m)
    #pragma unroll
    for (int rr = 0; rr < 4; ++rr) {
      const int o = obase + m * 16 + rr;
      const float bs = bias[o];
      #pragma unroll
      for (int nf = 0; nf < NF_; ++nf)
        ob[(size_t)o * LHW_ + nf * 16 + lr] = acc[m][nf][rr] + bs;
    }
}

// ---------------- fallback B (no ws at all): fp32-weight direct ----
#define SPT0_  64
#define BK0_   32
#define NKS0_  36
#define LDSW0_ 40
__global__ __launch_bounds__(256, 2) void conv_fb_kernel(
    const float* __restrict__ in, const float* __restrict__ wf,
    const float* __restrict__ bias, float* __restrict__ out)
{
  __shared__ u16 xs[SPT0_ * LDSW0_];
  const int tid = threadIdx.x;
  const int lane = tid & 63;
  const int wid = tid >> 6;
  const int lg = lane >> 4;
  const int lr = lane & 15;
  const int bid = blockIdx.x;
  const int b = bid / 49;
  const int l0 = (bid % 49) * SPT0_;
  const int sp = tid & 63;
  const int qq = tid >> 6;
  const int l = l0 + sp;
  const int y = l / HW_;
  const int x = l - y * HW_;
  const float* inb = in + (size_t)b * CIN_ * LHW_;
  f32x4 acc[4][4];
  #pragma unroll
  for (int i = 0; i < 4; ++i)
    #pragma unroll
    for (int j = 0; j < 4; ++j) acc[i][j] = f32x4{0.f, 0.f, 0.f, 0.f};
  auto stage_load = [&](int ks) -> uint4 {
    int kbase = ks * BK0_ + qq * 8;
    int c = kbase / 9;
    int t = kbase - c * 9;
    u16 v[8];
    #pragma unroll
    for (int j = 0; j < 8; ++j) {
      int dy = (t * 11) >> 5;
      int dx = t - 3 * dy;
      int yy = y + dy - 1, xx = x + dx - 1;
      float f = 0.f;
      if ((unsigned)yy < (unsigned)HW_ && (unsigned)xx < (unsigned)HW_)
        f = inb[(c * HW_ + yy) * HW_ + xx];
      v[j] = f2bf(f);
      ++t; if (t == 9) { t = 0; ++c; }
    }
    uint4 r;
    r.x = pack2(v[0], v[1]); r.y = pack2(v[2], v[3]);
    r.z = pack2(v[4], v[5]); r.w = pack2(v[6], v[7]);
    return r;
  };
  uint4 st = stage_load(0);
  for (int ks = 0; ks < NKS0_; ++ks) {
    __syncthreads();
    *reinterpret_cast<uint4*>(&xs[sp * LDSW0_ + qq * 8]) = st;
    __syncthreads();
    if (ks + 1 < NKS0_) st = stage_load(ks + 1);
    const int k0 = ks * BK0_;
    short8v a[4];
    #pragma unroll
    for (int ai = 0; ai < 4; ++ai) {
      const int o = wid * 64 + ai * 16 + lr;
      const float* pp = wf + (size_t)o * KTOT_ + k0 + lg * 8;
      u16 t8[8];
      #pragma unroll
      for (int j = 0; j < 8; ++j) t8[j] = f2bf(pp[j]);
      union { uint4 u; short8v s; } cv;
      cv.u.x = pack2(t8[0], t8[1]); cv.u.y = pack2(t8[2], t8[3]);
      cv.u.z = pack2(t8[4], t8[5]); cv.u.w = pack2(t8[6], t8[7]);
      a[ai] = cv.s;
    }
    short8v bv[4];
    #pragma unroll
    for (int sj = 0; sj < 4; ++sj)
      bv[sj] = *reinterpret_cast<const short8v*>(&xs[(sj * 16 + lr) * LDSW0_ + lg * 8]);
    #pragma unroll
    for (int ai = 0; ai < 4; ++ai)
      #pragma unroll
      for (int sj = 0; sj < 4; ++sj)
        acc[ai][sj] = __builtin_amdgcn_mfma_f32_16x16x32_bf16(a[ai], bv[sj], acc[ai][sj], 0, 0, 0);
  }
  float* outb = out + (size_t)b * COUT_ * LHW_ + l0;
  #pragma unroll
  for (int ai = 0; ai < 4; ++ai)
    #pragma unroll
    for (int r = 0; r < 4; ++r) {
      const int o = wid * 64 + ai * 16 + lg * 4 + r;
      const float bvs = bias[o];
      #pragma unroll
      for (int sj = 0; sj < 4; ++sj)
        outb[(size_t)o * LHW_ + sj * 16 + lr] = acc[ai][sj][r] + bvs;
    }
}

extern "C" void kernel_launch(void* const* d_in, const int* in_sizes, int n_in,
                              void* d_out, int out_size, void* d_ws, size_t ws_size,
                              hipStream_t stream) {
  (void)in_sizes; (void)n_in; (void)out_size;
  const float* in   = (const float*)d_in[0];
  const float* w    = (const float*)d_in[1];
  const float* bias = (const float*)d_in[2];
  float* out = (float*)d_out;

  const size_t wbytes  = (size_t)COUT_ * KTOT_ * sizeof(u16);        // 589824
  const size_t xbytes  = (size_t)16 * LHW_ * CIN_ * sizeof(u16);     // 12845056
  const size_t need    = wbytes + xbytes + 256;

  if (ws_size >= need) {
    u16* wb5 = (u16*)d_ws;
    u16* xin = wb5 + wbytes / 2;
    u16* zp  = xin + xbytes / 2;
    wreorder5_kernel<<<dim3(288), dim3(256), 0, stream>>>(w, wb5, zp);
    nhwc_kernel<<<dim3(784), dim3(256), 0, stream>>>(in, xin);
    conv12_kernel<<<dim3(784), dim3(256), 0, stream>>>(xin, wb5, bias, zp, out);
  } else if (ws_size >= wbytes) {
    u16* wb = (u16*)d_ws;
    wreorder_kernel<<<dim3(288), dim3(256), 0, stream>>>(w, wb);
    conv2_kernel<<<dim3(896), dim3(256), 0, stream>>>(in, wb, bias, out);
  } else {
    conv_fb_kernel<<<dim3(784), dim3(256), 0, stream>>>(in, w, bias, out);
  }
}